// Round 12
// baseline (238.786 us; speedup 1.0000x reference)
//
#include <hip/hip_runtime.h>

#define D 64
#define TPB 256
#define EPB 2048            // edges per build chunk
#define EPT (EPB / TPB)     // 8 edges per thread
#define BINSZ 64            // nodes per bin (bin = dst >> 6)
#define BINSHIFT 6
#define NBIN_MAX 1280       // LDS sizing (actual 1250)
#define NSEG 8              // cursor segments (= XCDs heuristically)
#define CAP 1536            // sorted-stage capacity per bin (mean 1024, 16 sigma)

__device__ __forceinline__ int xcd_chunk(int phys, int nblk)
{
    int q = nblk >> 3, r = nblk & 7;
    int xcd = phys & 7, sub = phys >> 3;
    return (xcd < r ? xcd * (q + 1) : r * (q + 1) + (xcd - r) * q) + sub;
}

__device__ __forceinline__ unsigned short f2bf(float f)
{
    unsigned u = __float_as_uint(f);
    return (unsigned short)((u + 0x7FFFu + ((u >> 16) & 1u)) >> 16);   // RNE
}

// ---------------- K0: feats fp32 -> bf16 (halves gather bytes) ----------------
__global__ __launch_bounds__(TPB) void cast_bf16_kernel(
    const float4* __restrict__ in, ushort4* __restrict__ outp, int n4)
{
    int i = blockIdx.x * TPB + threadIdx.x;
    int stride = gridDim.x * TPB;
    for (; i < n4; i += stride) {
        float4 v = in[i];
        ushort4 o;
        o.x = f2bf(v.x); o.y = f2bf(v.y); o.z = f2bf(v.z); o.w = f2bf(v.w);
        outp[i] = o;
    }
}

// ---------------- K1: per-(bin,seg) histogram (global atomics) ----------------
// seg = blockIdx&7: stable across kernels; round-robin dispatch puts same-seg
// blocks on the same XCD, so later claimed runs merge in that XCD's L2.
__global__ __launch_bounds__(TPB, 4) void binhist8_kernel(
    const int* __restrict__ dst, int* __restrict__ counts8,
    int n_edges, int nbin, int eb)
{
    __shared__ int hist[NBIN_MAX];
    int t = threadIdx.x;
    int blk = xcd_chunk(blockIdx.x, eb);
    int seg = blockIdx.x & (NSEG - 1);
    for (int i = t; i < nbin; i += TPB) hist[i] = 0;
    __syncthreads();
    int base = blk * EPB;
    #pragma unroll
    for (int k = 0; k < EPT; ++k) {
        int e = base + k * TPB + t;
        if (e < n_edges) atomicAdd(&hist[dst[e] >> BINSHIFT], 1);
    }
    __syncthreads();
    for (int i = t; i < nbin; i += TPB)
        if (hist[i] > 0) atomicAdd(&counts8[i * NSEG + seg], hist[i]);
}

// ---------------- K2: single-block exclusive scan of 10000 counts ----------------
// In-place: counts8 -> bases; also copies to cursor for the claim phase.
__global__ __launch_bounds__(1024) void scan8_kernel(
    int* __restrict__ data, int* __restrict__ cursor, int n)
{
    __shared__ int tsum[1024];
    const int NPT = 10;   // 1024*10 = 10240 >= 10000
    int t = threadIdx.x;
    int base = t * NPT;
    int v[NPT];
    #pragma unroll
    for (int i = 0; i < NPT; ++i)
        v[i] = (base + i < n) ? data[base + i] : 0;
    int tot = 0;
    #pragma unroll
    for (int i = 0; i < NPT; ++i) tot += v[i];
    tsum[t] = tot;
    __syncthreads();
    for (int off = 1; off < 1024; off <<= 1) {
        int x = (t >= off) ? tsum[t - off] : 0;
        __syncthreads();
        tsum[t] += x;
        __syncthreads();
    }
    int run = tsum[t] - tot;
    #pragma unroll
    for (int i = 0; i < NPT; ++i) {
        if (base + i < n) { data[base + i] = run; cursor[base + i] = run; }
        run += v[i];
    }
}

// ---------------- K3: bin-scatter with LDS reorder + atomic run claims ----------------
__global__ __launch_bounds__(TPB, 4) void binscatter8_kernel(
    const int* __restrict__ src, const int* __restrict__ dst,
    const float* __restrict__ edge_w, int* __restrict__ cursor,
    uint2* __restrict__ csr, int n_edges, int nbin, int eb)
{
    __shared__ int lb[NBIN_MAX + 1];
    __shared__ int cur[NBIN_MAX];           // local cursors, then run deltas
    __shared__ unsigned short binof[EPB];
    __shared__ uint2 stage[EPB];
    __shared__ int tv[TPB];

    int t = threadIdx.x;
    int blk = xcd_chunk(blockIdx.x, eb);    // same mapping as binhist8
    int seg = blockIdx.x & (NSEG - 1);      // same seg as binhist8

    for (int i = t; i < nbin + 1; i += TPB) lb[i] = 0;
    __syncthreads();

    int base = blk * EPB;
    int d[EPT], s[EPT]; float w[EPT];
    #pragma unroll
    for (int k = 0; k < EPT; ++k) {
        int e = base + k * TPB + t;
        bool ok = (e < n_edges);
        d[k] = ok ? dst[e] : -1;
        s[k] = ok ? src[e] : 0;
        w[k] = ok ? edge_w[e] : 0.0f;
        if (ok) atomicAdd(&lb[d[k] >> BINSHIFT], 1);
    }
    __syncthreads();

    // local exclusive scan of lb[0..nbin); total -> lb[nbin]. 5 bins/thread.
    const int NPT = (NBIN_MAX + TPB - 1) / TPB;   // 5
    int b0 = t * NPT;
    int v[NPT];
    #pragma unroll
    for (int i = 0; i < NPT; ++i)
        v[i] = (b0 + i < nbin) ? lb[b0 + i] : 0;
    int tot = 0;
    #pragma unroll
    for (int i = 0; i < NPT; ++i) tot += v[i];
    tv[t] = tot;
    __syncthreads();
    for (int off = 1; off < TPB; off <<= 1) {
        int x = (t >= off) ? tv[t - off] : 0;
        __syncthreads();
        tv[t] += x;
        __syncthreads();
    }
    int run = tv[t] - tot;
    #pragma unroll
    for (int i = 0; i < NPT; ++i) {
        if (b0 + i < nbin) lb[b0 + i] = run;
        run += v[i];
    }
    if (t == TPB - 1) lb[nbin] = tv[t];
    __syncthreads();

    for (int i = t; i < nbin; i += TPB) cur[i] = lb[i];
    __syncthreads();

    #pragma unroll
    for (int k = 0; k < EPT; ++k) {
        if (d[k] >= 0) {
            int bin = d[k] >> BINSHIFT;
            int pos = atomicAdd(&cur[bin], 1);
            stage[pos] = make_uint2((unsigned)s[k] | ((unsigned)(d[k] & (BINSZ - 1)) << 17),
                                    __float_as_uint(w[k]));
            binof[pos] = (unsigned short)bin;
        }
    }
    __syncthreads();

    // claim a contiguous run per non-empty bin; cur[b] := global_base - local_base
    for (int b = t; b < nbin; b += TPB) {
        int c = lb[b + 1] - lb[b];
        if (c > 0) {
            int g = atomicAdd(&cursor[b * NSEG + seg], c);
            cur[b] = g - lb[b];
        }
    }
    __syncthreads();

    int nval = lb[nbin];
    for (int p = t; p < nval; p += TPB)
        csr[cur[binof[p]] + p] = stage[p];
}

// ---------------- K4: per-bin counting-sort + register-accumulate gather ----------------
// bf16 neighbor gather (2B/lane); fp32 self-term for the 0.8 path.
__global__ __launch_bounds__(TPB, 4) void bin_gather_kernel(
    const float* __restrict__ feats, const unsigned short* __restrict__ fb,
    const int* __restrict__ bases, const uint2* __restrict__ csr,
    float* __restrict__ agg, int n_nodes, int n_edges, int nbin)
{
    __shared__ uint2 stage[CAP];
    __shared__ int   cnt[BINSZ];
    __shared__ int   off[BINSZ + 1];

    int t = threadIdx.x, lane = t & 63, wv = t >> 6;
    int bin = blockIdx.x;
    int lo  = bin << BINSHIFT;

    int seg0 = bases[bin * NSEG];
    int seg1 = (bin + 1 < nbin) ? bases[(bin + 1) * NSEG] : n_edges;
    int total = seg1 - seg0;

    if (t < BINSZ) cnt[t] = 0;
    __syncthreads();

    for (int i = t; i < total; i += TPB)
        atomicAdd(&cnt[csr[seg0 + i].x >> 17], 1);
    __syncthreads();

    if (wv == 0) {
        int c = (lane < BINSZ) ? cnt[lane] : 0;
        int x = c;
        #pragma unroll
        for (int o = 1; o < 64; o <<= 1) {
            int y = __shfl_up(x, o);
            if (lane >= o) x += y;
        }
        if (lane == 0) off[0] = 0;
        if (lane < BINSZ) {
            off[lane + 1] = x;
            cnt[lane]     = x - c;
        }
    }
    __syncthreads();

    for (int i = t; i < total; i += TPB) {
        uint2 r = csr[seg0 + i];
        int pos = atomicAdd(&cnt[r.x >> 17], 1);
        if (pos < CAP) stage[pos] = r;
    }
    __syncthreads();

    for (int nl = wv; nl < BINSZ; nl += 4) {
        int n = lo + nl;
        if (n >= n_nodes) break;
        int i  = off[nl];
        int e2 = off[nl + 1];
        float acc = 0.0f, sumw = 0.0f;
        for (; i + 8 <= e2; i += 8) {
            uint2 r0 = stage[i + 0], r1 = stage[i + 1], r2 = stage[i + 2], r3 = stage[i + 3];
            uint2 r4 = stage[i + 4], r5 = stage[i + 5], r6 = stage[i + 6], r7 = stage[i + 7];
            float f0 = __uint_as_float((unsigned)fb[(r0.x & 0x1FFFF) * D + lane] << 16);
            float f1 = __uint_as_float((unsigned)fb[(r1.x & 0x1FFFF) * D + lane] << 16);
            float f2 = __uint_as_float((unsigned)fb[(r2.x & 0x1FFFF) * D + lane] << 16);
            float f3 = __uint_as_float((unsigned)fb[(r3.x & 0x1FFFF) * D + lane] << 16);
            float f4 = __uint_as_float((unsigned)fb[(r4.x & 0x1FFFF) * D + lane] << 16);
            float f5 = __uint_as_float((unsigned)fb[(r5.x & 0x1FFFF) * D + lane] << 16);
            float f6 = __uint_as_float((unsigned)fb[(r6.x & 0x1FFFF) * D + lane] << 16);
            float f7 = __uint_as_float((unsigned)fb[(r7.x & 0x1FFFF) * D + lane] << 16);
            float w0 = __uint_as_float(r0.y), w1 = __uint_as_float(r1.y);
            float w2 = __uint_as_float(r2.y), w3 = __uint_as_float(r3.y);
            float w4 = __uint_as_float(r4.y), w5 = __uint_as_float(r5.y);
            float w6 = __uint_as_float(r6.y), w7 = __uint_as_float(r7.y);
            acc = fmaf(w0, f0, acc); acc = fmaf(w1, f1, acc);
            acc = fmaf(w2, f2, acc); acc = fmaf(w3, f3, acc);
            acc = fmaf(w4, f4, acc); acc = fmaf(w5, f5, acc);
            acc = fmaf(w6, f6, acc); acc = fmaf(w7, f7, acc);
            sumw += (w0 + w1) + (w2 + w3) + ((w4 + w5) + (w6 + w7));
        }
        for (; i < e2; ++i) {
            uint2 r = stage[i];
            float w = __uint_as_float(r.y);
            acc = fmaf(w, __uint_as_float((unsigned)fb[(r.x & 0x1FFFF) * D + lane] << 16), acc);
            sumw += w;
        }
        float f = feats[n * D + lane];   // fp32 self-term (0.8 path stays exact)
        float h = (sumw > 0.0f) ? acc / fmaxf(sumw, 1e-30f) : 0.0f;
        agg[n * D + lane] = 0.8f * f + 0.2f * h;
    }
}

// ---------------- K5: 64x64 GEMM + bias + sigmoid (in-place on d_out) ----------------
__global__ __launch_bounds__(TPB, 4) void gemm_sigmoid_kernel(
    const float* __restrict__ Wm, const float* __restrict__ bv,
    float* __restrict__ io, int n_nodes)
{
    int lane = threadIdx.x & 63;
    int wave = (blockIdx.x * blockDim.x + threadIdx.x) >> 6;
    int nw   = (gridDim.x * blockDim.x) >> 6;

    float wcol[D];
    #pragma unroll
    for (int k = 0; k < D; ++k) wcol[k] = Wm[k * D + lane];
    float bias = bv[lane];

    for (int n = wave; n < n_nodes; n += nw) {
        float a = io[n * D + lane];
        float r = bias;
        #pragma unroll
        for (int k = 0; k < D; ++k) {
            float ak = __uint_as_float(
                __builtin_amdgcn_readlane(__float_as_uint(a), k));
            r = fmaf(ak, wcol[k], r);
        }
        io[n * D + lane] = 1.0f / (1.0f + __expf(-r));
    }
}

extern "C" void kernel_launch(void* const* d_in, const int* in_sizes, int n_in,
                              void* d_out, int out_size, void* d_ws, size_t ws_size,
                              hipStream_t stream)
{
    const float* feats  = (const float*)d_in[0];
    const int*   src    = (const int*)d_in[1];
    const int*   dst    = (const int*)d_in[2];
    const float* edge_w = (const float*)d_in[3];
    const float* W      = (const float*)d_in[4];
    const float* b      = (const float*)d_in[5];
    float*       out    = (float*)d_out;

    const int n_nodes = in_sizes[0] / D;
    const int n_edges = in_sizes[1];

    const int NBIN = (n_nodes + BINSZ - 1) / BINSZ;   // 1250
    const int EB   = (n_edges + EPB - 1) / EPB;       // 625
    const int NCTR = NBIN * NSEG;                     // 10000

    // ---- workspace: fb16[N*D] + bases[10016] + cursor[10016] + csr[E] (~20.6MB) ----
    unsigned short* fb = (unsigned short*)d_ws;                 // [n_nodes*D] bf16
    int* bases  = (int*)(fb + (size_t)n_nodes * D);             // [10016] counts->bases
    int* cursor = bases + 10016;                                // [10016]
    uint2* csr  = (uint2*)(cursor + 10016);                     // [n_edges] (8B aligned)

    hipMemsetAsync(bases, 0, NCTR * sizeof(int), stream);

    cast_bf16_kernel<<<2048, TPB, 0, stream>>>((const float4*)feats, (ushort4*)fb,
                                               n_nodes * D / 4);
    binhist8_kernel<<<EB, TPB, 0, stream>>>(dst, bases, n_edges, NBIN, EB);
    scan8_kernel<<<1, 1024, 0, stream>>>(bases, cursor, NCTR);
    binscatter8_kernel<<<EB, TPB, 0, stream>>>(src, dst, edge_w, cursor, csr,
                                               n_edges, NBIN, EB);
    bin_gather_kernel<<<NBIN, TPB, 0, stream>>>(feats, fb, bases, csr, out,
                                                n_nodes, n_edges, NBIN);
    gemm_sigmoid_kernel<<<1024, TPB, 0, stream>>>(W, b, out, n_nodes);
}

// Round 13
// 215.903 us; speedup vs baseline: 1.1060x; 1.1060x over previous
//
#include <hip/hip_runtime.h>

#define D 64
#define TPB 256
#define EPB 2048            // edges per build chunk
#define EPT (EPB / TPB)     // 8 edges per thread
#define BINSZ 64            // nodes per bin (bin = dst >> 6)
#define BINSHIFT 6
#define NBIN_MAX 1280       // LDS sizing (actual 1250)
#define SCAN_ITEMS 8
#define CAP 1536            // sorted-stage capacity per bin (mean 1024, 16 sigma)

// bijective chunked XCD swizzle (m204): same-XCD blocks own CONTIGUOUS logical
// chunks; binhist and binscatter MUST use the same mapping so a bin's runs
// from same-XCD blocks are adjacent in csr (partial lines merge in that L2).
__device__ __forceinline__ int xcd_chunk(int phys, int nblk)
{
    int q = nblk >> 3, r = nblk & 7;
    int xcd = phys & 7, sub = phys >> 3;
    return (xcd < r ? xcd * (q + 1) : r * (q + 1) + (xcd - r) * q) + sub;
}

// ---------------- K1: per-(chunk,bin) histogram (plain strided writes) ----------------
__global__ __launch_bounds__(TPB, 4) void binhist_kernel(
    const int* __restrict__ dst, int* __restrict__ blockbin,
    int n_edges, int nbin, int eb)
{
    __shared__ int hist[NBIN_MAX];
    int t = threadIdx.x;
    int blk = xcd_chunk(blockIdx.x, eb);
    for (int i = t; i < nbin; i += TPB) hist[i] = 0;
    __syncthreads();
    int base = blk * EPB;
    #pragma unroll
    for (int k = 0; k < EPT; ++k) {
        int e = base + k * TPB + t;
        if (e < n_edges) atomicAdd(&hist[dst[e] >> BINSHIFT], 1);
    }
    __syncthreads();
    for (int i = t; i < nbin; i += TPB) blockbin[i * eb + blk] = hist[i];
}

// ---------------- 3-kernel exclusive scan (in-place) ----------------
__global__ __launch_bounds__(TPB) void scan_up(
    int* __restrict__ data, int* __restrict__ partials, int n)
{
    __shared__ int tsum[TPB];
    int t = threadIdx.x;
    int base = blockIdx.x * (TPB * SCAN_ITEMS) + t * SCAN_ITEMS;
    int v[SCAN_ITEMS];
    #pragma unroll
    for (int i = 0; i < SCAN_ITEMS; ++i)
        v[i] = (base + i < n) ? data[base + i] : 0;
    int tot = 0;
    #pragma unroll
    for (int i = 0; i < SCAN_ITEMS; ++i) tot += v[i];
    tsum[t] = tot;
    __syncthreads();
    for (int off = 1; off < TPB; off <<= 1) {
        int x = (t >= off) ? tsum[t - off] : 0;
        __syncthreads();
        tsum[t] += x;
        __syncthreads();
    }
    if (t == TPB - 1) partials[blockIdx.x] = tsum[t];
    int run = tsum[t] - tot;
    #pragma unroll
    for (int i = 0; i < SCAN_ITEMS; ++i) {
        if (base + i < n) data[base + i] = run;
        run += v[i];
    }
}

__global__ __launch_bounds__(1024) void scan_mid(int* __restrict__ partials, int nb)
{
    __shared__ int tsum[1024];
    int t = threadIdx.x;
    int v = (t < nb) ? partials[t] : 0;
    tsum[t] = v;
    __syncthreads();
    for (int off = 1; off < 1024; off <<= 1) {
        int x = (t >= off) ? tsum[t - off] : 0;
        __syncthreads();
        tsum[t] += x;
        __syncthreads();
    }
    if (t < nb) partials[t] = tsum[t] - v;   // exclusive
}

__global__ __launch_bounds__(TPB) void scan_down(
    int* __restrict__ data, const int* __restrict__ partials, int n)
{
    int t = threadIdx.x;
    int base = blockIdx.x * (TPB * SCAN_ITEMS) + t * SCAN_ITEMS;
    int add = partials[blockIdx.x];
    #pragma unroll
    for (int i = 0; i < SCAN_ITEMS; ++i)
        if (base + i < n) data[base + i] += add;
}

// ---------------- K5: bin-scatter with LDS reorder (deterministic) ----------------
__global__ __launch_bounds__(TPB, 4) void binscatter_kernel(
    const int* __restrict__ src, const int* __restrict__ dst,
    const float* __restrict__ edge_w, const int* __restrict__ scanned,
    uint2* __restrict__ csr, int n_edges, int nbin, int eb)
{
    __shared__ int lb[NBIN_MAX + 1];
    __shared__ int cur[NBIN_MAX];
    __shared__ unsigned short binof[EPB];
    __shared__ uint2 stage[EPB];
    __shared__ int tv[TPB];

    int t = threadIdx.x;
    int blk = xcd_chunk(blockIdx.x, eb);   // same mapping as binhist

    for (int i = t; i < nbin + 1; i += TPB) lb[i] = 0;
    __syncthreads();

    int base = blk * EPB;
    int d[EPT], s[EPT]; float w[EPT];
    #pragma unroll
    for (int k = 0; k < EPT; ++k) {
        int e = base + k * TPB + t;
        bool ok = (e < n_edges);
        d[k] = ok ? dst[e] : -1;
        s[k] = ok ? src[e] : 0;
        w[k] = ok ? edge_w[e] : 0.0f;
        if (ok) atomicAdd(&lb[d[k] >> BINSHIFT], 1);
    }
    __syncthreads();

    // local exclusive scan of lb[0..nbin); total -> lb[nbin]. 5 bins/thread.
    const int NPT = (NBIN_MAX + TPB - 1) / TPB;   // 5
    int b0 = t * NPT;
    int v[NPT];
    #pragma unroll
    for (int i = 0; i < NPT; ++i)
        v[i] = (b0 + i < nbin) ? lb[b0 + i] : 0;
    int tot = 0;
    #pragma unroll
    for (int i = 0; i < NPT; ++i) tot += v[i];
    tv[t] = tot;
    __syncthreads();
    for (int off = 1; off < TPB; off <<= 1) {
        int x = (t >= off) ? tv[t - off] : 0;
        __syncthreads();
        tv[t] += x;
        __syncthreads();
    }
    int run = tv[t] - tot;
    #pragma unroll
    for (int i = 0; i < NPT; ++i) {
        if (b0 + i < nbin) lb[b0 + i] = run;
        run += v[i];
    }
    if (t == TPB - 1) lb[nbin] = tv[t];
    __syncthreads();

    for (int i = t; i < nbin; i += TPB) cur[i] = lb[i];
    __syncthreads();

    #pragma unroll
    for (int k = 0; k < EPT; ++k) {
        if (d[k] >= 0) {
            int bin = d[k] >> BINSHIFT;
            int pos = atomicAdd(&cur[bin], 1);
            // pack: src (17b) | dst_local (6b) << 17
            stage[pos] = make_uint2((unsigned)s[k] | ((unsigned)(d[k] & (BINSZ - 1)) << 17),
                                    __float_as_uint(w[k]));
            binof[pos] = (unsigned short)bin;
        }
    }
    __syncthreads();

    int nval = lb[nbin];
    for (int p = t; p < nval; p += TPB) {
        int bin = binof[p];
        int gpos = scanned[bin * eb + blk] + (p - lb[bin]);
        csr[gpos] = stage[p];
    }
}

// ---------------- K6: counting-sort + register gather + FUSED GEMM+sigmoid ----------------
// R10's proven gather (VGPR=20) + gemm epilogue. wcol[64] + gather working set
// ~110 VGPR, under the 128 budget of __launch_bounds__(256,4) -> no spill.
// Saves the 41MB agg round-trip and one dispatch.
__global__ __launch_bounds__(TPB, 4) void bin_gather_fused_kernel(
    const float* __restrict__ feats, const int* __restrict__ scanned,
    const uint2* __restrict__ csr, const float* __restrict__ Wm,
    const float* __restrict__ bv, float* __restrict__ out,
    int n_nodes, int n_edges, int nbin, int eb)
{
    __shared__ uint2 stage[CAP];     // 12 KiB sorted records
    __shared__ int   cnt[BINSZ];
    __shared__ int   off[BINSZ + 1];

    int t = threadIdx.x, lane = t & 63, wv = t >> 6;
    int bin = blockIdx.x;
    int lo  = bin << BINSHIFT;

    float wcol[D];
    #pragma unroll
    for (int k = 0; k < D; ++k) wcol[k] = Wm[k * D + lane];
    float bias = bv[lane];

    int seg0 = scanned[bin * eb];
    int seg1 = (bin + 1 < nbin) ? scanned[(bin + 1) * eb] : n_edges;
    int total = seg1 - seg0;

    if (t < BINSZ) cnt[t] = 0;
    __syncthreads();

    // pass 1: histogram by dst_local
    for (int i = t; i < total; i += TPB)
        atomicAdd(&cnt[csr[seg0 + i].x >> 17], 1);
    __syncthreads();

    // wave 0: shfl scan -> off[], cursors
    if (wv == 0) {
        int c = (lane < BINSZ) ? cnt[lane] : 0;
        int x = c;
        #pragma unroll
        for (int o = 1; o < 64; o <<= 1) {
            int y = __shfl_up(x, o);
            if (lane >= o) x += y;
        }
        if (lane == 0) off[0] = 0;
        if (lane < BINSZ) {
            off[lane + 1] = x;
            cnt[lane]     = x - c;
        }
    }
    __syncthreads();

    // pass 2: scatter into sorted LDS stage
    for (int i = t; i < total; i += TPB) {
        uint2 r = csr[seg0 + i];
        int pos = atomicAdd(&cnt[r.x >> 17], 1);
        if (pos < CAP) stage[pos] = r;
    }
    __syncthreads();

    // phase B: gather with 8 named-scalar edges in flight, then fused epilogue
    for (int nl = wv; nl < BINSZ; nl += 4) {
        int n = lo + nl;
        if (n >= n_nodes) break;
        int i  = off[nl];
        int e2 = off[nl + 1];
        float acc = 0.0f, sumw = 0.0f;
        for (; i + 8 <= e2; i += 8) {
            uint2 r0 = stage[i + 0], r1 = stage[i + 1], r2 = stage[i + 2], r3 = stage[i + 3];
            uint2 r4 = stage[i + 4], r5 = stage[i + 5], r6 = stage[i + 6], r7 = stage[i + 7];
            float f0 = feats[(r0.x & 0x1FFFF) * D + lane];
            float f1 = feats[(r1.x & 0x1FFFF) * D + lane];
            float f2 = feats[(r2.x & 0x1FFFF) * D + lane];
            float f3 = feats[(r3.x & 0x1FFFF) * D + lane];
            float f4 = feats[(r4.x & 0x1FFFF) * D + lane];
            float f5 = feats[(r5.x & 0x1FFFF) * D + lane];
            float f6 = feats[(r6.x & 0x1FFFF) * D + lane];
            float f7 = feats[(r7.x & 0x1FFFF) * D + lane];
            float w0 = __uint_as_float(r0.y), w1 = __uint_as_float(r1.y);
            float w2 = __uint_as_float(r2.y), w3 = __uint_as_float(r3.y);
            float w4 = __uint_as_float(r4.y), w5 = __uint_as_float(r5.y);
            float w6 = __uint_as_float(r6.y), w7 = __uint_as_float(r7.y);
            acc = fmaf(w0, f0, acc); acc = fmaf(w1, f1, acc);
            acc = fmaf(w2, f2, acc); acc = fmaf(w3, f3, acc);
            acc = fmaf(w4, f4, acc); acc = fmaf(w5, f5, acc);
            acc = fmaf(w6, f6, acc); acc = fmaf(w7, f7, acc);
            sumw += (w0 + w1) + (w2 + w3) + ((w4 + w5) + (w6 + w7));
        }
        for (; i < e2; ++i) {
            uint2 r = stage[i];
            float w = __uint_as_float(r.y);
            acc = fmaf(w, feats[(r.x & 0x1FFFF) * D + lane], acc);
            sumw += w;
        }
        float f = feats[n * D + lane];
        float h = (sumw > 0.0f) ? acc / fmaxf(sumw, 1e-30f) : 0.0f;
        float aggv = 0.8f * f + 0.2f * h;

        // fused 64x64 GEMM row via readlane broadcast + bias + sigmoid
        float r = bias;
        #pragma unroll
        for (int k = 0; k < D; ++k) {
            float ak = __uint_as_float(
                __builtin_amdgcn_readlane(__float_as_uint(aggv), k));
            r = fmaf(ak, wcol[k], r);
        }
        out[n * D + lane] = 1.0f / (1.0f + __expf(-r));
    }
}

extern "C" void kernel_launch(void* const* d_in, const int* in_sizes, int n_in,
                              void* d_out, int out_size, void* d_ws, size_t ws_size,
                              hipStream_t stream)
{
    const float* feats  = (const float*)d_in[0];
    const int*   src    = (const int*)d_in[1];
    const int*   dst    = (const int*)d_in[2];
    const float* edge_w = (const float*)d_in[3];
    const float* W      = (const float*)d_in[4];
    const float* b      = (const float*)d_in[5];
    float*       out    = (float*)d_out;

    const int n_nodes = in_sizes[0] / D;
    const int n_edges = in_sizes[1];

    const int NBIN = (n_nodes + BINSZ - 1) / BINSZ;           // 1250
    const int EB   = (n_edges + EPB - 1) / EPB;               // 625
    const int NBB  = NBIN * EB;                               // 781,250
    const int nb   = (NBB + TPB * SCAN_ITEMS - 1) / (TPB * SCAN_ITEMS);  // 382 (<=1024)

    // ---- workspace: blockbin[NBB] (scanned in-place) + partials + csr (13.4MB, proven) ----
    int* ws_i     = (int*)d_ws;
    int* blockbin = ws_i;                         // [NBB]
    int* partials = blockbin + NBB;               // [1024]
    uint2* csr    = (uint2*)(partials + 1024);    // [n_edges] (NBB+1024 even -> 8B aligned)

    binhist_kernel<<<EB, TPB, 0, stream>>>(dst, blockbin, n_edges, NBIN, EB);
    scan_up<<<nb, TPB, 0, stream>>>(blockbin, partials, NBB);
    scan_mid<<<1, 1024, 0, stream>>>(partials, nb);
    scan_down<<<nb, TPB, 0, stream>>>(blockbin, partials, NBB);
    binscatter_kernel<<<EB, TPB, 0, stream>>>(src, dst, edge_w, blockbin, csr,
                                              n_edges, NBIN, EB);
    bin_gather_fused_kernel<<<NBIN, TPB, 0, stream>>>(feats, blockbin, csr, W, b,
                                                      out, n_nodes, n_edges, NBIN, EB);
}